// Round 14
// baseline (1047.020 us; speedup 1.0000x reference)
//
#include <hip/hip_runtime.h>

#define N_NODES_C   50000
#define N_EDGES_C   1600000
#define FEAT        128
#define NREL        8
#define NBUCKETS    400000
#define KTOT        1024
#define TILE        16                 // nodes per block; 50000 = 3125*16 exactly

// ---------------- workspace layout (bytes) ----------------
#define WS_COUNTS   0          // u32[100000] (u8x4 packed)     400,000
#define WS_OFFSETS  400000     // u32[400001] (+sentinel)     1,600,016
#define WS_RANK     2000016    // u8[1.6M]; dead after scatter -> probe scratch
#define WS_BSUM     3600016    // u32[512]                        2,048
#define WS_BOFF     3602064    // u32[512]                        2,048
#define WS_SORTED   3604112    // u32[1.6M]                   6,400,000
#define WS_HB       10004112   // int8[50000*128]             6,400,000
#define WS_WT       22804112   // bf16[128][1024]               262,144
#define WS_GMAX     23066256   // f32[1]                              4
#define WS_PMAX     23066260   // f32[3125]                      12,500
#define WS_NEEDED   23078760

typedef __attribute__((ext_vector_type(8))) short bf16x8;
typedef __attribute__((ext_vector_type(4))) float f32x4;

__device__ __forceinline__ unsigned short f2bf(float f) {
    unsigned u = __float_as_uint(f);
    return (unsigned short)((u + 0x7fffu + ((u >> 16) & 1u)) >> 16);  // RNE
}

__global__ void k_zero(unsigned* __restrict__ counts) {
    int i = blockIdx.x * 256 + threadIdx.x;
    if (i < 25000) ((uint4*)counts)[i] = make_uint4(0u, 0u, 0u, 0u);
}

__global__ void k_gmax1(const float* __restrict__ h, float* __restrict__ pmax) {
    __shared__ float s[4];
    int i = (blockIdx.x * 256 + threadIdx.x) * 8;
    float4 v0 = *(const float4*)&h[i];
    float4 v1 = *(const float4*)&h[i + 4];
    float m = fmaxf(fmaxf(fmaxf(fabsf(v0.x), fabsf(v0.y)), fmaxf(fabsf(v0.z), fabsf(v0.w))),
                    fmaxf(fmaxf(fabsf(v1.x), fabsf(v1.y)), fmaxf(fabsf(v1.z), fabsf(v1.w))));
#pragma unroll
    for (int o = 32; o > 0; o >>= 1) m = fmaxf(m, __shfl_xor(m, o));
    if ((threadIdx.x & 63) == 0) s[threadIdx.x >> 6] = m;
    __syncthreads();
    if (threadIdx.x == 0)
        pmax[blockIdx.x] = fmaxf(fmaxf(s[0], s[1]), fmaxf(s[2], s[3]));
}

__global__ void k_gmax2(const float* __restrict__ pmax, float* __restrict__ gmax) {
    __shared__ float s[1024];
    int t = threadIdx.x;
    float m = 0.f;
    for (int i = t; i < 3125; i += 1024) m = fmaxf(m, pmax[i]);
    s[t] = m;
    __syncthreads();
    for (int o = 512; o > 0; o >>= 1) {
        if (t < o) s[t] = fmaxf(s[t], s[t + o]);
        __syncthreads();
    }
    if (t == 0) gmax[0] = s[0];
}

__global__ void k_histprep(const int* __restrict__ dst, const int* __restrict__ et,
                           unsigned* __restrict__ counts, unsigned char* __restrict__ rank,
                           const float* __restrict__ h, unsigned char* __restrict__ hb8,
                           const float* __restrict__ W, unsigned short* __restrict__ wt,
                           const float* __restrict__ gmax) {
    int b = blockIdx.x, t = threadIdx.x;
    if (b < 6250) {
        int e = b * 256 + t;
        if (e < N_EDGES_C) {
            int key = dst[e] * NREL + et[e];
            int sh = 8 * (key & 3);
            unsigned old = atomicAdd(&counts[key >> 2], 1u << sh);
            rank[e] = (unsigned char)((old >> sh) & 0xffu);
        }
    } else if (b < 6250 + 3125) {
        float am = gmax[0];
        float inv = (am > 0.f) ? 127.f / am : 0.f;
        int i = ((b - 6250) * 256 + t) * 8;
        float4 v0 = *(const float4*)&h[i];
        float4 v1 = *(const float4*)&h[i + 4];
        float vv[8] = {v0.x, v0.y, v0.z, v0.w, v1.x, v1.y, v1.z, v1.w};
        unsigned q[8];
#pragma unroll
        for (int k = 0; k < 8; k++) {
            float qa = rintf(vv[k] * inv);
            qa = fmaxf(-127.f, fminf(127.f, qa));
            q[k] = (unsigned)((int)qa) & 0xffu;
        }
        unsigned lo = q[0] | (q[1] << 8) | (q[2] << 16) | (q[3] << 24);
        unsigned hi = q[4] | (q[5] << 8) | (q[6] << 16) | (q[7] << 24);
        *(uint2*)&hb8[i] = make_uint2(lo, hi);
    } else {
        int i = (b - 9375) * 256 + t;
        int n = i >> 10, rk = i & 1023;
        wt[i] = f2bf(W[rk * FEAT + n]);
    }
}

__global__ void k_scan_a(const unsigned* __restrict__ counts, unsigned* __restrict__ bsum) {
    __shared__ unsigned s[1024];
    int t = threadIdx.x;
    int i = blockIdx.x * 1024 + t;
    unsigned v = 0;
    if (i < NBUCKETS) v = (counts[i >> 2] >> (8 * (i & 3))) & 0xffu;
    s[t] = v;
    __syncthreads();
    for (int o = 512; o > 0; o >>= 1) {
        if (t < o) s[t] += s[t + o];
        __syncthreads();
    }
    if (t == 0) bsum[blockIdx.x] = s[0];
}

__global__ void k_scan_b(const unsigned* __restrict__ bsum, unsigned* __restrict__ boff, int nb) {
    __shared__ unsigned s[512];
    int t = threadIdx.x;
    unsigned v = (t < nb) ? bsum[t] : 0u;
    s[t] = v;
    __syncthreads();
    for (int o = 1; o < 512; o <<= 1) {
        unsigned u = (t >= o) ? s[t - o] : 0u;
        __syncthreads();
        s[t] += u;
        __syncthreads();
    }
    if (t < nb) boff[t] = s[t] - v;
}

__global__ void k_scan_c(const unsigned* __restrict__ counts, const unsigned* __restrict__ boff,
                         unsigned* __restrict__ offsets) {
    __shared__ unsigned s[1024];
    int t = threadIdx.x;
    int i = blockIdx.x * 1024 + t;
    unsigned v = 0;
    if (i < NBUCKETS) v = (counts[i >> 2] >> (8 * (i & 3))) & 0xffu;
    s[t] = v;
    __syncthreads();
    for (int o = 1; o < 1024; o <<= 1) {
        unsigned u = (t >= o) ? s[t - o] : 0u;
        __syncthreads();
        s[t] += u;
        __syncthreads();
    }
    if (i < NBUCKETS) offsets[i] = boff[blockIdx.x] + s[t] - v;
    if (i == NBUCKETS) offsets[i] = N_EDGES_C;   // sentinel
}

__global__ void k_scatter(const int* __restrict__ src, const int* __restrict__ dst,
                          const int* __restrict__ et, const float* __restrict__ norm,
                          const unsigned* __restrict__ offsets,
                          const unsigned char* __restrict__ rank,
                          unsigned* __restrict__ sorted) {
    int e = blockIdx.x * 256 + threadIdx.x;
    if (e < N_EDGES_C) {
        int key = dst[e] * NREL + et[e];
        unsigned pos = offsets[key] + (unsigned)rank[e];
        sorted[pos] = ((unsigned)src[e] << 16) | (unsigned)f2bf(norm[e]);
    }
}

// ---- main fused kernel: IDENTICAL to R11/R12 (clean 150 µs reference) ----
__global__ __launch_bounds__(512) void k_fused(const unsigned* __restrict__ sorted,
                                               const unsigned* __restrict__ offsets,
                                               const unsigned char* __restrict__ hb8,
                                               const unsigned short* __restrict__ wt,
                                               const float* __restrict__ bias,
                                               float* __restrict__ out,
                                               const float* __restrict__ gmax) {
    __shared__ char At[32768];
    __shared__ float csLds[TILE][NREL];
    int t = threadIdx.x, w = t >> 6, lane = t & 63;
    int node0 = blockIdx.x * TILE;
    int grp = lane >> 4, ln16 = lane & 15;
    float gs = gmax[0] * (1.f / 127.f);

    int kbase = (node0 + 2 * w) * NREL;
    unsigned bnds = offsets[kbase + (lane <= 16 ? lane : 16)];
    unsigned pp   = __shfl(bnds, 0);
    unsigned send = __shfl(bnds, 16);
    int j = 0;
    unsigned bend = (unsigned)__builtin_amdgcn_readlane((int)bnds, 1);
    float a0 = 0.f, a1 = 0.f, cs = 0.f;

#define FLUSHJ(JJ, A0, A1, CS)                                                 \
    do {                                                                       \
        int row_ = 2 * w + ((JJ) >> 3);                                        \
        int jr_  = (JJ) & 7;                                                   \
        *(unsigned*)(At + row_ * 2048 +                                        \
                     ((jr_ * 256 + lane * 4) ^ ((row_ & 7) << 4))) =           \
            (unsigned)f2bf((A0) * gs) | ((unsigned)f2bf((A1) * gs) << 16);     \
        if (lane == 0) csLds[row_][jr_] = (CS);                                \
    } while (0)

    {
        unsigned q0 = pp + lane;
        unsigned recv = __builtin_nontemporal_load(
            &sorted[q0 < N_EDGES_C ? q0 : (N_EDGES_C - 1)]);
        unsigned wstart = pp;
        while (wstart < send) {
            unsigned qn = wstart + 64 + lane;
            unsigned recv_n = __builtin_nontemporal_load(
                &sorted[qn < N_EDGES_C ? qn : (N_EDGES_C - 1)]);
#pragma unroll 1
            for (int b = 0; b < 4; b++) {
                unsigned short hv[16];
                float nvv[16];
#pragma unroll
                for (int u = 0; u < 16; u++) {
                    unsigned ru = (unsigned)__builtin_amdgcn_readlane((int)recv, b * 16 + u);
                    nvv[u] = __uint_as_float((ru & 0xffffu) << 16);
                    const unsigned char* rp = hb8 + (size_t)(ru >> 16) * FEAT;
                    hv[u] = *(const unsigned short*)(rp + lane * 2);
                }
#pragma unroll
                for (int u = 0; u < 16; u++) {
                    unsigned gpos = wstart + (unsigned)(b * 16 + u);
                    if (gpos >= send) goto stream_done;
                    while (gpos >= bend) {
                        FLUSHJ(j, a0, a1, cs);
                        a0 = a1 = cs = 0.f;
                        j++;
                        bend = (unsigned)__builtin_amdgcn_readlane(
                            (int)bnds, j < 16 ? j + 1 : 16);
                    }
                    int hvv = (int)(unsigned)hv[u];
                    int q0i = (hvv << 24) >> 24;
                    int q1i = (hvv << 16) >> 24;
                    a0 += nvv[u] * (float)q0i;
                    a1 += nvv[u] * (float)q1i;
                    cs += nvv[u];
                }
            }
            wstart += 64;
            recv = recv_n;
        }
    stream_done:;
    }
    while (j < 16) {
        FLUSHJ(j, a0, a1, cs);
        a0 = a1 = cs = 0.f;
        j++;
    }
#undef FLUSHJ
    __syncthreads();

    f32x4 acc = (f32x4){0.f, 0.f, 0.f, 0.f};
    const unsigned short* wcol = wt + (size_t)(w * 16 + ln16) * KTOT + grp * 8;
#pragma unroll 8
    for (int ks = 0; ks < 32; ks++) {
        bf16x8 af = *(const bf16x8*)(At + ln16 * 2048 +
                                     ((ks * 64 + grp * 16) ^ ((ln16 & 7) << 4)));
        bf16x8 bf = *(const bf16x8*)(wcol + ks * 32);
        acc = __builtin_amdgcn_mfma_f32_16x16x32_bf16(af, bf, acc, 0, 0, 0);
    }

#pragma unroll
    for (int i = 0; i < 4; i++) {
        int rl = grp * 4 + i;
        int g  = node0 + rl;
        int col = w * 16 + ln16;
        float v = acc[i];
#pragma unroll
        for (int rr = 0; rr < NREL; rr++) v += csLds[rl][rr] * bias[rr * FEAT + col];
        __builtin_nontemporal_store(fmaxf(v, 0.f), &out[(size_t)g * FEAT + col]);
    }
}

// ---- probe kernels, BIG GRID so they land in top-5 (divide dur by multiplier).
// V1 (x4): full aggregation. V3 (x8): current gather pattern + keep-alive.
// V5 (x8): 4-records-per-instruction group-gather (16 lanes x dwordx2 = one
//          int8 row; 4 rows per 64-lane load) -> tests VMEM-instr-rate cap.
template <int V>
__global__ __launch_bounds__(512) void k_probe(const unsigned* __restrict__ sorted,
                                               const unsigned* __restrict__ offsets,
                                               const unsigned char* __restrict__ hb8,
                                               float* __restrict__ scratch,
                                               const float* __restrict__ gmax) {
    __shared__ char At[32768];
    __shared__ float csLds[TILE][NREL];
    int t = threadIdx.x, w = t >> 6, lane = t & 63;
    int tile = blockIdx.x % 3125;
    int node0 = tile * TILE;
    float gs = gmax[0] * (1.f / 127.f);

    int kbase = (node0 + 2 * w) * NREL;
    unsigned bnds = offsets[kbase + (lane <= 16 ? lane : 16)];
    unsigned pp   = __shfl(bnds, 0);
    unsigned send = __shfl(bnds, 16);
    int j = 0;
    unsigned bend = (unsigned)__builtin_amdgcn_readlane((int)bnds, 1);
    float a0 = 0.f, a1 = 0.f, cs = 0.f;

#define FLUSHJ(JJ, A0, A1, CS)                                                 \
    do {                                                                       \
        int row_ = 2 * w + ((JJ) >> 3);                                        \
        int jr_  = (JJ) & 7;                                                   \
        *(unsigned*)(At + row_ * 2048 +                                        \
                     ((jr_ * 256 + lane * 4) ^ ((row_ & 7) << 4))) =           \
            (unsigned)f2bf((A0) * gs) | ((unsigned)f2bf((A1) * gs) << 16);     \
        if (lane == 0) csLds[row_][jr_] = (CS);                                \
    } while (0)

    if (V == 5) {
        // group-gather: 64-record window; 16 loads fetch all 64 rows
        unsigned q0 = pp + lane;
        unsigned recv = __builtin_nontemporal_load(
            &sorted[q0 < N_EDGES_C ? q0 : (N_EDGES_C - 1)]);
        unsigned wstart = pp;
        int g16 = lane >> 4;                  // group 0..3
        int fo  = (lane & 15) * 8;            // 8-byte feature slice
        while (wstart < send) {
            unsigned qn = wstart + 64 + lane;
            unsigned recv_n = __builtin_nontemporal_load(
                &sorted[qn < N_EDGES_C ? qn : (N_EDGES_C - 1)]);
#pragma unroll
            for (int s = 0; s < 16; s++) {
                unsigned r4 = (unsigned)__shfl((int)recv, s * 4 + g16);  // bpermute
                const unsigned char* rp = hb8 + (size_t)(r4 >> 16) * FEAT + fo;
                uint2 v = *(const uint2*)rp;          // 1 instr = 4 records' rows
                asm volatile("" :: "v"(v.x), "v"(v.y));
                cs += (float)(r4 & 1u);
            }
            wstart += 64;
            recv = recv_n;
        }
        if (lane == 0) scratch[150000 + (size_t)blockIdx.x * 8 + w] = cs;
        return;
    }

    {
        unsigned q0 = pp + lane;
        unsigned recv = __builtin_nontemporal_load(
            &sorted[q0 < N_EDGES_C ? q0 : (N_EDGES_C - 1)]);
        unsigned wstart = pp;
        while (wstart < send) {
            unsigned qn = wstart + 64 + lane;
            unsigned recv_n = __builtin_nontemporal_load(
                &sorted[qn < N_EDGES_C ? qn : (N_EDGES_C - 1)]);
#pragma unroll 1
            for (int b = 0; b < 4; b++) {
                unsigned short hv[16];
                float nvv[16];
#pragma unroll
                for (int u = 0; u < 16; u++) {
                    unsigned ru = (unsigned)__builtin_amdgcn_readlane((int)recv, b * 16 + u);
                    nvv[u] = __uint_as_float((ru & 0xffffu) << 16);
                    const unsigned char* rp = hb8 + (size_t)(ru >> 16) * FEAT;
                    hv[u] = *(const unsigned short*)(rp + lane * 2);
                }
#pragma unroll
                for (int u = 0; u < 16; u++) {
                    unsigned gpos = wstart + (unsigned)(b * 16 + u);
                    if (gpos >= send) goto sdone;
                    if (V == 1) {
                        while (gpos >= bend) {
                            FLUSHJ(j, a0, a1, cs);
                            a0 = a1 = cs = 0.f;
                            j++;
                            bend = (unsigned)__builtin_amdgcn_readlane(
                                (int)bnds, j < 16 ? j + 1 : 16);
                        }
                        int hvv = (int)(unsigned)hv[u];
                        int q0i = (hvv << 24) >> 24;
                        int q1i = (hvv << 16) >> 24;
                        a0 += nvv[u] * (float)q0i;
                        a1 += nvv[u] * (float)q1i;
                        cs += nvv[u];
                    } else {
                        cs += nvv[u];
                        asm volatile("" :: "v"((unsigned)hv[u]));
                    }
                }
            }
            wstart += 64;
            recv = recv_n;
        }
    sdone:
        if (V == 1) {
            while (j < 16) {
                FLUSHJ(j, a0, a1, cs);
                a0 = a1 = cs = 0.f;
                j++;
            }
            __syncthreads();
            float keep = csLds[lane & 15][w] +
                         (float)(*(unsigned*)(At + ((t * 64) & 32767)));
            if (lane == 0) scratch[(size_t)blockIdx.x * 8 + w] = keep;
        } else {
            if (lane == 0) scratch[(size_t)100000 + blockIdx.x * 8 + w] = cs;
        }
    }
#undef FLUSHJ
}

extern "C" void kernel_launch(void* const* d_in, const int* in_sizes, int n_in,
                              void* d_out, int out_size, void* d_ws, size_t ws_size,
                              hipStream_t stream) {
    const float* h    = (const float*)d_in[0];
    const int*   src  = (const int*)d_in[1];
    const int*   dst  = (const int*)d_in[2];
    const int*   et   = (const int*)d_in[3];
    const float* norm = (const float*)d_in[4];
    const float* W    = (const float*)d_in[5];
    const float* b    = (const float*)d_in[6];
    float*       out  = (float*)d_out;

    if (ws_size < (size_t)WS_NEEDED) return;

    char* ws = (char*)d_ws;
    unsigned*       counts  = (unsigned*)(ws + WS_COUNTS);
    unsigned*       offsets = (unsigned*)(ws + WS_OFFSETS);
    unsigned char*  rank    = (unsigned char*)(ws + WS_RANK);
    float*          scratch = (float*)(ws + WS_RANK);   // rank dead after scatter
    unsigned*       bsum    = (unsigned*)(ws + WS_BSUM);
    unsigned*       boff    = (unsigned*)(ws + WS_BOFF);
    unsigned*       sorted  = (unsigned*)(ws + WS_SORTED);
    unsigned char*  hb8     = (unsigned char*)(ws + WS_HB);
    unsigned short* wt      = (unsigned short*)(ws + WS_WT);
    float*          gmax    = (float*)(ws + WS_GMAX);
    float*          pmax    = (float*)(ws + WS_PMAX);

    int nb = (NBUCKETS + 1023) / 1024;   // 391

    k_zero<<<98, 256, 0, stream>>>(counts);
    k_gmax1<<<3125, 256, 0, stream>>>(h, pmax);
    k_gmax2<<<1, 1024, 0, stream>>>(pmax, gmax);
    k_histprep<<<6250 + 3125 + 512, 256, 0, stream>>>(dst, et, counts, rank,
                                                      h, hb8, W, wt, gmax);
    k_scan_a<<<nb, 1024, 0, stream>>>(counts, bsum);
    k_scan_b<<<1, 512, 0, stream>>>(bsum, boff, nb);
    k_scan_c<<<nb, 1024, 0, stream>>>(counts, boff, offsets);
    k_scatter<<<6250, 256, 0, stream>>>(src, dst, et, norm, offsets, rank, sorted);

    k_fused<<<N_NODES_C / TILE, 512, 0, stream>>>(sorted, offsets, hb8, wt, b, out,
                                                  gmax);
    // probes (profiling only; grid-multiplied to surface in top-5)
    k_probe<1><<<4 * 3125, 512, 0, stream>>>(sorted, offsets, hb8, scratch, gmax);
    k_probe<3><<<8 * 3125, 512, 0, stream>>>(sorted, offsets, hb8, scratch, gmax);
    k_probe<5><<<8 * 3125, 512, 0, stream>>>(sorted, offsets, hb8, scratch, gmax);
}

// Round 15
// 274.451 us; speedup vs baseline: 3.8150x; 3.8150x over previous
//
#include <hip/hip_runtime.h>

#define N_NODES_C   50000
#define N_EDGES_C   1600000
#define FEAT        128
#define NREL        8
#define NBUCKETS    400000
#define KTOT        1024
#define TILE        16                 // nodes per block; 50000 = 3125*16 exactly

// ---------------- workspace layout (bytes) ----------------
#define WS_COUNTS   0          // u32[100000] (u8x4 packed)     400,000
#define WS_OFFSETS  400000     // u32[400001] (+sentinel)     1,600,016
#define WS_RANK     2000016    // u8[1.6M]                    1,600,000
#define WS_BSUM     3600016    // u32[512]                        2,048
#define WS_BOFF     3602064    // u32[512]                        2,048
#define WS_SORTED   3604112    // u32[1.6M]                   6,400,000
#define WS_HB       10004112   // int8[50000*128]             6,400,000
#define WS_WT       22804112   // bf16[128][1024]               262,144
#define WS_GMAX     23066256   // f32[1]                              4
#define WS_PMAX     23066260   // f32[3125]                      12,500
#define WS_NEEDED   23078760

typedef __attribute__((ext_vector_type(8))) short bf16x8;
typedef __attribute__((ext_vector_type(4))) float f32x4;

__device__ __forceinline__ unsigned short f2bf(float f) {
    unsigned u = __float_as_uint(f);
    return (unsigned short)((u + 0x7fffu + ((u >> 16) & 1u)) >> 16);  // RNE
}

__global__ void k_zero(unsigned* __restrict__ counts) {
    int i = blockIdx.x * 256 + threadIdx.x;
    if (i < 25000) ((uint4*)counts)[i] = make_uint4(0u, 0u, 0u, 0u);
}

__global__ void k_gmax1(const float* __restrict__ h, float* __restrict__ pmax) {
    __shared__ float s[4];
    int i = (blockIdx.x * 256 + threadIdx.x) * 8;
    float4 v0 = *(const float4*)&h[i];
    float4 v1 = *(const float4*)&h[i + 4];
    float m = fmaxf(fmaxf(fmaxf(fabsf(v0.x), fabsf(v0.y)), fmaxf(fabsf(v0.z), fabsf(v0.w))),
                    fmaxf(fmaxf(fabsf(v1.x), fabsf(v1.y)), fmaxf(fabsf(v1.z), fabsf(v1.w))));
#pragma unroll
    for (int o = 32; o > 0; o >>= 1) m = fmaxf(m, __shfl_xor(m, o));
    if ((threadIdx.x & 63) == 0) s[threadIdx.x >> 6] = m;
    __syncthreads();
    if (threadIdx.x == 0)
        pmax[blockIdx.x] = fmaxf(fmaxf(s[0], s[1]), fmaxf(s[2], s[3]));
}

__global__ void k_gmax2(const float* __restrict__ pmax, float* __restrict__ gmax) {
    __shared__ float s[1024];
    int t = threadIdx.x;
    float m = 0.f;
    for (int i = t; i < 3125; i += 1024) m = fmaxf(m, pmax[i]);
    s[t] = m;
    __syncthreads();
    for (int o = 512; o > 0; o >>= 1) {
        if (t < o) s[t] = fmaxf(s[t], s[t + o]);
        __syncthreads();
    }
    if (t == 0) gmax[0] = s[0];
}

// rel-major key: key = et*50000 + dst  (wave's rows x 1 rel = contiguous stream)
__global__ void k_histprep(const int* __restrict__ dst, const int* __restrict__ et,
                           unsigned* __restrict__ counts, unsigned char* __restrict__ rank,
                           const float* __restrict__ h, unsigned char* __restrict__ hb8,
                           const float* __restrict__ W, unsigned short* __restrict__ wt,
                           const float* __restrict__ gmax) {
    int b = blockIdx.x, t = threadIdx.x;
    if (b < 6250) {
        int e = b * 256 + t;
        if (e < N_EDGES_C) {
            int key = et[e] * N_NODES_C + dst[e];
            int sh = 8 * (key & 3);
            unsigned old = atomicAdd(&counts[key >> 2], 1u << sh);
            rank[e] = (unsigned char)((old >> sh) & 0xffu);
        }
    } else if (b < 6250 + 3125) {
        float am = gmax[0];
        float inv = (am > 0.f) ? 127.f / am : 0.f;
        int i = ((b - 6250) * 256 + t) * 8;
        float4 v0 = *(const float4*)&h[i];
        float4 v1 = *(const float4*)&h[i + 4];
        float vv[8] = {v0.x, v0.y, v0.z, v0.w, v1.x, v1.y, v1.z, v1.w};
        unsigned q[8];
#pragma unroll
        for (int k = 0; k < 8; k++) {
            float qa = rintf(vv[k] * inv);
            qa = fmaxf(-127.f, fminf(127.f, qa));
            q[k] = (unsigned)((int)qa) & 0xffu;
        }
        unsigned lo = q[0] | (q[1] << 8) | (q[2] << 16) | (q[3] << 24);
        unsigned hi = q[4] | (q[5] << 8) | (q[6] << 16) | (q[7] << 24);
        *(uint2*)&hb8[i] = make_uint2(lo, hi);
    } else {
        int i = (b - 9375) * 256 + t;
        int n = i >> 10, rk = i & 1023;
        wt[i] = f2bf(W[rk * FEAT + n]);
    }
}

__global__ void k_scan_a(const unsigned* __restrict__ counts, unsigned* __restrict__ bsum) {
    __shared__ unsigned s[1024];
    int t = threadIdx.x;
    int i = blockIdx.x * 1024 + t;
    unsigned v = 0;
    if (i < NBUCKETS) v = (counts[i >> 2] >> (8 * (i & 3))) & 0xffu;
    s[t] = v;
    __syncthreads();
    for (int o = 512; o > 0; o >>= 1) {
        if (t < o) s[t] += s[t + o];
        __syncthreads();
    }
    if (t == 0) bsum[blockIdx.x] = s[0];
}

__global__ void k_scan_b(const unsigned* __restrict__ bsum, unsigned* __restrict__ boff, int nb) {
    __shared__ unsigned s[512];
    int t = threadIdx.x;
    unsigned v = (t < nb) ? bsum[t] : 0u;
    s[t] = v;
    __syncthreads();
    for (int o = 1; o < 512; o <<= 1) {
        unsigned u = (t >= o) ? s[t - o] : 0u;
        __syncthreads();
        s[t] += u;
        __syncthreads();
    }
    if (t < nb) boff[t] = s[t] - v;
}

__global__ void k_scan_c(const unsigned* __restrict__ counts, const unsigned* __restrict__ boff,
                         unsigned* __restrict__ offsets) {
    __shared__ unsigned s[1024];
    int t = threadIdx.x;
    int i = blockIdx.x * 1024 + t;
    unsigned v = 0;
    if (i < NBUCKETS) v = (counts[i >> 2] >> (8 * (i & 3))) & 0xffu;
    s[t] = v;
    __syncthreads();
    for (int o = 1; o < 1024; o <<= 1) {
        unsigned u = (t >= o) ? s[t - o] : 0u;
        __syncthreads();
        s[t] += u;
        __syncthreads();
    }
    if (i < NBUCKETS) offsets[i] = boff[blockIdx.x] + s[t] - v;
    if (i == NBUCKETS) offsets[i] = N_EDGES_C;   // sentinel
}

__global__ void k_scatter(const int* __restrict__ src, const int* __restrict__ dst,
                          const int* __restrict__ et, const float* __restrict__ norm,
                          const unsigned* __restrict__ offsets,
                          const unsigned char* __restrict__ rank,
                          unsigned* __restrict__ sorted) {
    int e = blockIdx.x * 256 + threadIdx.x;
    if (e < N_EDGES_C) {
        int key = et[e] * N_NODES_C + dst[e];
        unsigned pos = offsets[key] + (unsigned)rank[e];
        sorted[pos] = ((unsigned)src[e] << 16) | (unsigned)f2bf(norm[e]);
    }
}

// Fused aggregate+GEMM, TILE=16, 256 threads = 4 waves, 8 blocks/CU.
// Per relation r: wave w stream-aggregates its 4 contiguous (r, node) buckets
// (rel-major sort) into a 4KB LDS tile; barrier; MFMA K=128 accumulating into
// persistent acc; barrier; next rel. 16 short phases x 8 staggered blocks/CU
// desynchronizes memory demand (R13 probes: this pattern sustains 3 TB/s).
__global__ __launch_bounds__(256, 8) void k_fused(const unsigned* __restrict__ sorted,
                                                  const unsigned* __restrict__ offsets,
                                                  const unsigned char* __restrict__ hb8,
                                                  const unsigned short* __restrict__ wt,
                                                  const float* __restrict__ bias,
                                                  float* __restrict__ out,
                                                  const float* __restrict__ gmax) {
    __shared__ char At[4096];             // [16 rows][128 k] bf16, XOR-swizzled
    __shared__ float csLds[TILE][NREL];
    int t = threadIdx.x, w = t >> 6, lane = t & 63;
    int node0 = blockIdx.x * TILE;
    int grp = lane >> 4, ln16 = lane & 15;
    float gs = gmax[0] * (1.f / 127.f);

    // 40 boundaries: rel r, idx i in 0..4 -> offsets[r*50000 + node0 + w*4 + i]
    int li = (lane < 40) ? lane : 39;
    unsigned allb = offsets[(li / 5) * N_NODES_C + node0 + w * 4 + (li % 5)];

    f32x4 acc[2];
    acc[0] = (f32x4){0.f, 0.f, 0.f, 0.f};
    acc[1] = (f32x4){0.f, 0.f, 0.f, 0.f};

#pragma unroll 1
    for (int r = 0; r < NREL; r++) {
        unsigned pp   = (unsigned)__builtin_amdgcn_readlane((int)allb, r * 5);
        unsigned send = (unsigned)__builtin_amdgcn_readlane((int)allb, r * 5 + 4);
        int j = 0;
        unsigned bend = (unsigned)__builtin_amdgcn_readlane((int)allb, r * 5 + 1);
        float a0 = 0.f, a1 = 0.f, cs = 0.f;

#define FLUSHJ(JJ, A0, A1, CS)                                                 \
    do {                                                                       \
        int row_ = w * 4 + (JJ);                                               \
        *(unsigned*)(At + ((row_ * 256 + lane * 4) ^ ((row_ & 7) << 4))) =     \
            (unsigned)f2bf((A0) * gs) | ((unsigned)f2bf((A1) * gs) << 16);     \
        if (lane == 0) csLds[row_][r] = (CS);                                  \
    } while (0)

        {
            unsigned q0 = pp + lane;
            unsigned recv = __builtin_nontemporal_load(
                &sorted[q0 < N_EDGES_C ? q0 : (N_EDGES_C - 1)]);
            unsigned wstart = pp;
            while (wstart < send) {
                unsigned qn = wstart + 64 + lane;
                unsigned recv_n = __builtin_nontemporal_load(
                    &sorted[qn < N_EDGES_C ? qn : (N_EDGES_C - 1)]);
#pragma unroll 1
                for (int b = 0; b < 4; b++) {
                    unsigned short hv[16];
                    float nvv[16];
#pragma unroll
                    for (int u = 0; u < 16; u++) {
                        unsigned ru = (unsigned)__builtin_amdgcn_readlane(
                            (int)recv, b * 16 + u);
                        nvv[u] = __uint_as_float((ru & 0xffffu) << 16);
                        const unsigned char* rp = hb8 + (size_t)(ru >> 16) * FEAT;
                        hv[u] = *(const unsigned short*)(rp + lane * 2);
                    }
#pragma unroll
                    for (int u = 0; u < 16; u++) {
                        unsigned gpos = wstart + (unsigned)(b * 16 + u);
                        if (gpos >= send) goto stream_done;
                        while (gpos >= bend) {
                            FLUSHJ(j, a0, a1, cs);
                            a0 = a1 = cs = 0.f;
                            j++;
                            bend = (unsigned)__builtin_amdgcn_readlane(
                                (int)allb, r * 5 + (j < 4 ? j + 1 : 4));
                        }
                        int hvv = (int)(unsigned)hv[u];
                        int q0i = (hvv << 24) >> 24;
                        int q1i = (hvv << 16) >> 24;
                        a0 += nvv[u] * (float)q0i;
                        a1 += nvv[u] * (float)q1i;
                        cs += nvv[u];
                    }
                }
                wstart += 64;
                recv = recv_n;
            }
        stream_done:;
        }
        while (j < 4) {                    // flush trailing (incl. empty) buckets
            FLUSHJ(j, a0, a1, cs);
            a0 = a1 = cs = 0.f;
            j++;
        }
#undef FLUSHJ
        __syncthreads();

        // MFMA for this rel: K=128 (4 ksteps), wave covers 2 col-tiles
#pragma unroll
        for (int ks = 0; ks < 4; ks++) {
            bf16x8 af = *(const bf16x8*)(At + ((ln16 * 256 + ks * 64 + grp * 16) ^
                                               ((ln16 & 7) << 4)));
#pragma unroll
            for (int c = 0; c < 2; c++) {
                int col = (w * 2 + c) * 16 + ln16;
                bf16x8 bf = *(const bf16x8*)(wt + (size_t)col * KTOT + r * FEAT +
                                             ks * 32 + grp * 8);
                acc[c] = __builtin_amdgcn_mfma_f32_16x16x32_bf16(af, bf, acc[c], 0, 0, 0);
            }
        }
        __syncthreads();                   // protect At before next rel overwrites
    }

    // epilogue: bias via csum + ReLU. D map: col=lane&15, row=(lane>>4)*4+reg
#pragma unroll
    for (int i = 0; i < 4; i++) {
        int rl = grp * 4 + i;
        int g  = node0 + rl;
#pragma unroll
        for (int c = 0; c < 2; c++) {
            int col = (w * 2 + c) * 16 + ln16;
            float v = acc[c][i];
#pragma unroll
            for (int rr = 0; rr < NREL; rr++) v += csLds[rl][rr] * bias[rr * FEAT + col];
            __builtin_nontemporal_store(fmaxf(v, 0.f), &out[(size_t)g * FEAT + col]);
        }
    }
}

extern "C" void kernel_launch(void* const* d_in, const int* in_sizes, int n_in,
                              void* d_out, int out_size, void* d_ws, size_t ws_size,
                              hipStream_t stream) {
    const float* h    = (const float*)d_in[0];
    const int*   src  = (const int*)d_in[1];
    const int*   dst  = (const int*)d_in[2];
    const int*   et   = (const int*)d_in[3];
    const float* norm = (const float*)d_in[4];
    const float* W    = (const float*)d_in[5];
    const float* b    = (const float*)d_in[6];
    float*       out  = (float*)d_out;

    if (ws_size < (size_t)WS_NEEDED) return;

    char* ws = (char*)d_ws;
    unsigned*       counts  = (unsigned*)(ws + WS_COUNTS);
    unsigned*       offsets = (unsigned*)(ws + WS_OFFSETS);
    unsigned char*  rank    = (unsigned char*)(ws + WS_RANK);
    unsigned*       bsum    = (unsigned*)(ws + WS_BSUM);
    unsigned*       boff    = (unsigned*)(ws + WS_BOFF);
    unsigned*       sorted  = (unsigned*)(ws + WS_SORTED);
    unsigned char*  hb8     = (unsigned char*)(ws + WS_HB);
    unsigned short* wt      = (unsigned short*)(ws + WS_WT);
    float*          gmax    = (float*)(ws + WS_GMAX);
    float*          pmax    = (float*)(ws + WS_PMAX);

    int nb = (NBUCKETS + 1023) / 1024;   // 391

    k_zero<<<98, 256, 0, stream>>>(counts);
    k_gmax1<<<3125, 256, 0, stream>>>(h, pmax);
    k_gmax2<<<1, 1024, 0, stream>>>(pmax, gmax);
    k_histprep<<<6250 + 3125 + 512, 256, 0, stream>>>(dst, et, counts, rank,
                                                      h, hb8, W, wt, gmax);
    k_scan_a<<<nb, 1024, 0, stream>>>(counts, bsum);
    k_scan_b<<<1, 512, 0, stream>>>(bsum, boff, nb);
    k_scan_c<<<nb, 1024, 0, stream>>>(counts, boff, offsets);
    k_scatter<<<6250, 256, 0, stream>>>(src, dst, et, norm, offsets, rank, sorted);

    k_fused<<<N_NODES_C / TILE, 256, 0, stream>>>(sorted, offsets, hb8, wt, b, out,
                                                  gmax);
}